// Round 4
// baseline (197.120 us; speedup 1.0000x reference)
//
#include <hip/hip_runtime.h>
#include <math.h>

#define NBANDS 2049
#define NF 4096      // real frame size
#define NC 2048      // complex FFT size (rfft via packed complex)
#define BUF 1024     // input samples per batch row
#define THREADS 512
#define R2C 0.70710678118654752f

// LDS bank swizzle: bijective on [0,2048), keeps FFT/unpack patterns <=2-way
__device__ __forceinline__ int SW(int i) { return i ^ (i >> 2) ^ (i >> 6); }

// position of frequency k after DIF stages [4,4,4,4,4,2]
__device__ __forceinline__ int posrev(int k) {
  return ((k & 3) << 9) | (((k >> 2) & 3) << 7) | (((k >> 4) & 3) << 5) |
         (((k >> 6) & 3) << 3) | (((k >> 8) & 3) << 1) | ((k >> 10) & 1);
}

struct Smem {
  float xs[BUF];                 // 4 KB
  float zreA[NC], zimA[NC];      // 16 KB
  float zreB[NC], zimB[NC];      // 16 KB
};                               // 36 KB -> not the occupancy limiter

struct State {
  float2 W[5];                   // per-thread stage twiddles
  float2 Ub;                     // exp(-pi*i*tid/2048) for rfft unpack
  float ce, se, co, so;          // window base cos/sin at lvl0 resolution
  float s1a[5], s1b[5];          // running mins after lvl1 (two subtrees)
  float s2a[5], s2b[5];          // running mins after lvl2 (two live nodes)
  float o[4][5];                 // staged dB output columns
};

__device__ __forceinline__ float2 cmul(float2 a, float2 b) {
  return make_float2(a.x * b.x - a.y * b.y, a.x * b.y + a.y * b.x);
}

// Chebyshev cos-doubling: cos(t) -> cos(2^L * t)
template <int L>
__device__ __forceinline__ float cheb(float c) {
  #pragma unroll
  for (int i = 0; i < L; ++i) c = 2.0f * c * c - 1.0f;
  return c;
}

__device__ __forceinline__ void bfly4(float* __restrict__ re, float* __restrict__ im,
                                      int i0, int i1, int i2, int i3,
                                      float2 W, float2 W2, float2 W3) {
  float ar = re[i0], ai = im[i0];
  float br = re[i1], bi = im[i1];
  float cr = re[i2], ci = im[i2];
  float dr = re[i3], di = im[i3];
  float t0r = ar + cr, t0i = ai + ci;
  float t1r = ar - cr, t1i = ai - ci;
  float t2r = br + dr, t2i = bi + di;
  float t3r = br - dr, t3i = bi - di;
  re[i0] = t0r + t2r; im[i0] = t0i + t2i;
  float y1r = t1r + t3i, y1i = t1i - t3r;                  // (t1 - i*t3)
  re[i1] = y1r * W.x - y1i * W.y;  im[i1] = y1r * W.y + y1i * W.x;
  float y2r = t0r - t2r, y2i = t0i - t2i;
  re[i2] = y2r * W2.x - y2i * W2.y; im[i2] = y2r * W2.y + y2i * W2.x;
  float y3r = t1r - t3i, y3i = t1i + t3r;                  // (t1 + i*t3)
  re[i3] = y3r * W3.x - y3i * W3.y; im[i3] = y3r * W3.y + y3i * W3.x;
}

template <int LM, bool HASB>
__device__ __forceinline__ void radix4p(Smem& sm, float2 W) {
  const int j = threadIdx.x;
  const int m = 1 << LM;
  const int base = ((j >> LM) << (LM + 2)) | (j & (m - 1));
  const int i0 = SW(base), i1 = SW(base + m), i2 = SW(base + 2 * m), i3 = SW(base + 3 * m);
  float2 W2 = make_float2(W.x * W.x - W.y * W.y, 2.0f * W.x * W.y);
  float2 W3 = cmul(W, W2);
  bfly4(sm.zreA, sm.zimA, i0, i1, i2, i3, W, W2, W3);
  if constexpr (HASB) bfly4(sm.zreB, sm.zimB, i0, i1, i2, i3, W, W2, W3);
}

__device__ __forceinline__ float rpow(const float* __restrict__ re, const float* __restrict__ im,
                                      int p1, int p2, float2 U) {
  float zkr = re[p1], zki = im[p1];
  float zmr = re[p2], zmi = im[p2];
  float Ex = 0.5f * (zkr + zmr), Ey = 0.5f * (zki - zmi);
  float Ox = 0.5f * (zki + zmi), Oy = -0.5f * (zkr - zmr);
  float Fx = Ex + U.x * Ox - U.y * Oy;
  float Fy = Ey + U.x * Oy + U.y * Ox;
  return Fx * Fx + Fy * Fy;
}

// ACT: 0 s1a=min(p,1e6); 1 s1b=min(p,1e6); 2 lvl0 fold into s1a&s1b;
//      3 s2a=min(s1a,p); 4 s2b=min(s1a,p); 5 s2a=min(s1b,p); 6 s2b=min(s1b,p);
//      7 o[COL]=dB(min(s2a,p)); 8 o[COL]=dB(min(s2b,p))
template <int ACT, int COL>
__device__ __forceinline__ void act(State& st, int it, float p) {
  if constexpr (ACT == 0)      st.s1a[it] = fminf(p, 1.0e6f);
  else if constexpr (ACT == 1) st.s1b[it] = fminf(p, 1.0e6f);
  else if constexpr (ACT == 2) { st.s1a[it] = fminf(st.s1a[it], p); st.s1b[it] = fminf(st.s1b[it], p); }
  else if constexpr (ACT == 3) st.s2a[it] = fminf(st.s1a[it], p);
  else if constexpr (ACT == 4) st.s2b[it] = fminf(st.s1a[it], p);
  else if constexpr (ACT == 5) st.s2a[it] = fminf(st.s1b[it], p);
  else if constexpr (ACT == 6) st.s2b[it] = fminf(st.s1b[it], p);
  else if constexpr (ACT == 7) st.o[COL][it] = 10.0f * log10f(fmaxf(fminf(st.s2a[it], p), 1.0e-10f));
  else                         st.o[COL][it] = 10.0f * log10f(fmaxf(fminf(st.s2b[it], p), 1.0e-10f));
}

// One pass = two windowed frames (A at level LA offset offA, B at LB/offB),
// FFT'd together, unpacked, min-chain actions applied.
template <int LA, int ACTA, int COLA, int LB, int ACTB, int COLB, bool HASB>
__device__ __forceinline__ void pass(Smem& sm, State& st, int offA, int offB) {
  const int tid = threadIdx.x;
  __syncthreads();                          // prior pass done reading z arrays
  // ---- pack: z[n] = w(2n)*frame(2n) + i*w(2n+1)*frame(2n+1) ----
  #pragma unroll
  for (int it = 0; it < 4; ++it) {
    const int n = tid + it * THREADS;
    const int k = 2 * n;
    const float cbe = (it == 0) ? st.ce : (it == 1) ? -st.se : (it == 2) ? -st.ce : st.se;
    const float cbo = (it == 0) ? st.co : (it == 1) ? -st.so : (it == 2) ? -st.co : st.so;
    const int p = SW(n);
    {
      constexpr int M = NF >> LA;
      constexpr float ws = (float)(1 << LA) * (0.5f / 1024.0f);
      const int k0 = max(NF - offA, NF - M);
      float re = 0.0f, im = 0.0f;
      if (k >= k0) {
        const float2 xv = *(const float2*)&sm.xs[k - (NF - offA)];
        re = ws * (1.0f - cheb<LA>(cbe)) * xv.x;
        im = ws * (1.0f - cheb<LA>(cbo)) * xv.y;
      }
      sm.zreA[p] = re; sm.zimA[p] = im;
    }
    if constexpr (HASB) {
      constexpr int M = NF >> LB;
      constexpr float ws = (float)(1 << LB) * (0.5f / 1024.0f);
      const int k0 = max(NF - offB, NF - M);
      float re = 0.0f, im = 0.0f;
      if (k >= k0) {
        const float2 xv = *(const float2*)&sm.xs[k - (NF - offB)];
        re = ws * (1.0f - cheb<LB>(cbe)) * xv.x;
        im = ws * (1.0f - cheb<LB>(cbo)) * xv.y;
      }
      sm.zreB[p] = re; sm.zimB[p] = im;
    }
  }

  __syncthreads(); radix4p<9, HASB>(sm, st.W[0]);
  __syncthreads(); radix4p<7, HASB>(sm, st.W[1]);
  __syncthreads(); radix4p<5, HASB>(sm, st.W[2]);
  __syncthreads(); radix4p<3, HASB>(sm, st.W[3]);
  __syncthreads(); radix4p<1, HASB>(sm, st.W[4]);
  __syncthreads();
  // final twiddle-free radix-2 on adjacent pairs
  #pragma unroll
  for (int jj = 0; jj < 2; ++jj) {
    const int i = 2 * (tid + jj * THREADS);
    const int p0 = SW(i), p1 = SW(i + 1);
    {
      float ar = sm.zreA[p0], ai = sm.zimA[p0];
      float br = sm.zreA[p1], bi = sm.zimA[p1];
      sm.zreA[p0] = ar + br; sm.zimA[p0] = ai + bi;
      sm.zreA[p1] = ar - br; sm.zimA[p1] = ai - bi;
    }
    if constexpr (HASB) {
      float ar = sm.zreB[p0], ai = sm.zimB[p0];
      float br = sm.zreB[p1], bi = sm.zimB[p1];
      sm.zreB[p0] = ar + br; sm.zimB[p0] = ai + bi;
      sm.zreB[p1] = ar - br; sm.zimB[p1] = ai - bi;
    }
  }
  __syncthreads();

  // ---- unpack rfft bins + power + min-chain actions ----
  #pragma unroll
  for (int it = 0; it < 5; ++it) {
    if (it < 4 || tid == 0) {
      const int k = tid + it * THREADS;
      const int p1 = SW(posrev(k & (NC - 1)));
      const int p2 = SW(posrev((NC - k) & (NC - 1)));
      float2 U;
      if (it == 0)      U = st.Ub;
      else if (it == 1) U = cmul(st.Ub, make_float2(R2C, -R2C));
      else if (it == 2) U = make_float2(st.Ub.y, -st.Ub.x);
      else if (it == 3) U = cmul(st.Ub, make_float2(-R2C, -R2C));
      else              U = make_float2(-st.Ub.x, -st.Ub.y);
      const float pA = rpow(sm.zreA, sm.zimA, p1, p2, U);
      act<ACTA, COLA>(st, it, pA);
      if constexpr (HASB) {
        const float pB = rpow(sm.zreB, sm.zimB, p1, p2, U);
        act<ACTB, COLB>(st, it, pB);
      }
    }
  }
}

template <int T0>
__device__ __forceinline__ void store_cols(State& st, float* __restrict__ outb) {
  const int tid = threadIdx.x;
  #pragma unroll
  for (int it = 0; it < 5; ++it) {
    if (it < 4 || tid == 0) {
      const int band = tid + it * THREADS;
      float4 v = make_float4(st.o[0][it], st.o[1][it], st.o[2][it], st.o[3][it]);
      *(float4*)&outb[(size_t)band * 8 + T0] = v;
    }
  }
}

__global__ __launch_bounds__(THREADS, 4) void spec_kernel(const float* __restrict__ x,
                                                          float* __restrict__ out) {
  __shared__ Smem sm;
  State st;
  const int tid = threadIdx.x;
  const int b = blockIdx.x;
  const float* xb = x + (size_t)b * BUF;
  #pragma unroll
  for (int i = tid; i < BUF; i += THREADS) sm.xs[i] = xb[i];
  {
    float sn, cs;
    sincospif((float)tid * (1.0f / 1024.0f), &sn, &cs);
    st.W[0] = make_float2(cs, -sn); st.ce = cs; st.se = sn;
    sincospif((float)(tid & 127) * (1.0f / 256.0f), &sn, &cs);  st.W[1] = make_float2(cs, -sn);
    sincospif((float)(tid & 31) * (1.0f / 64.0f), &sn, &cs);    st.W[2] = make_float2(cs, -sn);
    sincospif((float)(tid & 7) * (1.0f / 16.0f), &sn, &cs);     st.W[3] = make_float2(cs, -sn);
    st.W[4] = (tid & 1) ? make_float2(R2C, -R2C) : make_float2(1.0f, 0.0f);
    sincospif((float)tid * (1.0f / 2048.0f), &sn, &cs);         st.Ub = make_float2(cs, -sn);
    sincospif((float)(2 * tid + 1) * (1.0f / 2048.0f), &sn, &cs); st.co = cs; st.so = sn;
  }
  float* outb = out + (size_t)b * (NBANDS * 8);

  // Frames: lvl0 off=1024; lvl1 off=512*(i+1); lvl2 off=256*(i+1); lvl3 off=128*(i+1)
  pass<1, 0, 0,  1, 1, 0, true >(sm, st, 512, 1024);   // s1a=l1_0, s1b=l1_1
  pass<0, 2, 0,  2, 3, 0, true >(sm, st, 1024, 256);   // fold lvl0; s2a=min(s1a,l2_0)
  pass<2, 4, 0,  3, 7, 0, true >(sm, st, 512, 128);    // s2b=min(s1a,l2_1); o0=dB(s2a,l3_0)
  pass<3, 7, 1,  3, 8, 2, true >(sm, st, 256, 384);    // o1=dB(s2a,l3_1); o2=dB(s2b,l3_2)
  pass<3, 8, 3,  2, 5, 0, true >(sm, st, 512, 768);    // o3=dB(s2b,l3_3); s2a=min(s1b,l2_2)
  store_cols<0>(st, outb);
  pass<2, 6, 0,  3, 7, 0, true >(sm, st, 1024, 640);   // s2b=min(s1b,l2_3); o0=dB(s2a,l3_4)
  pass<3, 7, 1,  3, 8, 2, true >(sm, st, 768, 896);    // o1=dB(s2a,l3_5); o2=dB(s2b,l3_6)
  pass<3, 8, 3,  0, 0, 0, false>(sm, st, 1024, 0);     // o3=dB(s2b,l3_7)
  store_cols<4>(st, outb);
}

extern "C" void kernel_launch(void* const* d_in, const int* in_sizes, int n_in,
                              void* d_out, int out_size, void* d_ws, size_t ws_size,
                              hipStream_t stream) {
  const float* x = (const float*)d_in[0];
  float* out = (float*)d_out;
  const int B = in_sizes[0] / BUF;
  hipLaunchKernelGGL(spec_kernel, dim3(B), dim3(THREADS), 0, stream, x, out);
}

// Round 5
// 125.432 us; speedup vs baseline: 1.5715x; 1.5715x over previous
//
#include <hip/hip_runtime.h>
#include <math.h>

#define NBANDS 2049
#define NF 4096      // real frame size
#define NC 2048      // complex FFT size (rfft via packed complex)
#define BUF 1024     // input samples per batch row
#define THREADS 512
#define R2C 0.70710678118654752f

// LDS bank swizzle: bijective on [0,2048), keeps FFT/unpack patterns <=2-way
__device__ __forceinline__ int SW(int i) { return i ^ (i >> 2) ^ (i >> 6); }

// digit-reversed position after 5 radix-4 stages (final radix-2 folded out);
// j in [0,1024)
__device__ __forceinline__ int posrev10(int j) {
  return ((j & 3) << 9) | (((j >> 2) & 3) << 7) | (((j >> 4) & 3) << 5) |
         (((j >> 6) & 3) << 3) | (((j >> 8) & 3) << 1);
}

struct Smem {
  float xs[BUF];                 // 4 KB
  float zreA[NC], zimA[NC];      // 16 KB
  float zreB[NC], zimB[NC];      // 16 KB
  float ob[4 * NBANDS];          // 32 KB output-column staging
};                               // ~68 KB -> 2 blocks/CU

struct State {
  float2 W[5];                   // per-thread stage twiddles
  float2 Ub;                     // exp(-pi*i*tid/2048) for rfft unpack
  float co, so;                  // odd-sample window base cos/sin
  float s1a[5], s1b[5];          // running mins after lvl1 (two subtrees)
  float s2a[5], s2b[5];          // running mins after lvl2 (two live nodes)
};

__device__ __forceinline__ float2 cmul(float2 a, float2 b) {
  return make_float2(a.x * b.x - a.y * b.y, a.x * b.y + a.y * b.x);
}

// Chebyshev cos-doubling: cos(t) -> cos(2^L * t)
template <int L>
__device__ __forceinline__ float cheb(float c) {
  #pragma unroll
  for (int i = 0; i < L; ++i) c = 2.0f * c * c - 1.0f;
  return c;
}

__device__ __forceinline__ void bfly4(float* __restrict__ re, float* __restrict__ im,
                                      int i0, int i1, int i2, int i3,
                                      float2 W, float2 W2, float2 W3) {
  float ar = re[i0], ai = im[i0];
  float br = re[i1], bi = im[i1];
  float cr = re[i2], ci = im[i2];
  float dr = re[i3], di = im[i3];
  float t0r = ar + cr, t0i = ai + ci;
  float t1r = ar - cr, t1i = ai - ci;
  float t2r = br + dr, t2i = bi + di;
  float t3r = br - dr, t3i = bi - di;
  re[i0] = t0r + t2r; im[i0] = t0i + t2i;
  float y1r = t1r + t3i, y1i = t1i - t3r;                  // (t1 - i*t3)
  re[i1] = y1r * W.x - y1i * W.y;  im[i1] = y1r * W.y + y1i * W.x;
  float y2r = t0r - t2r, y2i = t0i - t2i;
  re[i2] = y2r * W2.x - y2i * W2.y; im[i2] = y2r * W2.y + y2i * W2.x;
  float y3r = t1r - t3i, y3i = t1i + t3r;                  // (t1 + i*t3)
  re[i3] = y3r * W3.x - y3i * W3.y; im[i3] = y3r * W3.y + y3i * W3.x;
}

template <int LM, bool HASB>
__device__ __forceinline__ void radix4p(Smem& sm, float2 W) {
  const int j = threadIdx.x;
  const int m = 1 << LM;
  const int base = ((j >> LM) << (LM + 2)) | (j & (m - 1));
  const int i0 = SW(base), i1 = SW(base + m), i2 = SW(base + 2 * m), i3 = SW(base + 3 * m);
  float2 W2 = make_float2(W.x * W.x - W.y * W.y, 2.0f * W.x * W.y);
  float2 W3 = cmul(W, W2);
  bfly4(sm.zreA, sm.zimA, i0, i1, i2, i3, W, W2, W3);
  if constexpr (HASB) bfly4(sm.zreB, sm.zimB, i0, i1, i2, i3, W, W2, W3);
}

// rfft unpack with the final radix-2 folded in: Z[k] = D[e] + s*D[e^1]
__device__ __forceinline__ float rpow(const float* __restrict__ re, const float* __restrict__ im,
                                      int p1, float sA, int p2, float sB, float2 U) {
  float zkr = re[p1] + sA * re[p1 ^ 1];
  float zki = im[p1] + sA * im[p1 ^ 1];
  float zmr = re[p2] + sB * re[p2 ^ 1];
  float zmi = im[p2] + sB * im[p2 ^ 1];
  float Ex = 0.5f * (zkr + zmr), Ey = 0.5f * (zki - zmi);
  float Ox = 0.5f * (zki + zmi), Oy = -0.5f * (zkr - zmr);
  float Fx = Ex + U.x * Ox - U.y * Oy;
  float Fy = Ey + U.x * Oy + U.y * Ox;
  return Fx * Fx + Fy * Fy;
}

// ACT: 0 s1a=min(p,1e6); 1 s1b=min(p,1e6); 2 lvl0 fold into s1a&s1b;
//      3 s2a=min(s1a,p); 4 s2b=min(s1a,p); 5 s2a=min(s1b,p); 6 s2b=min(s1b,p);
//      7 ob[COL]=dB(min(s2a,p)); 8 ob[COL]=dB(min(s2b,p))
template <int ACT, int COL>
__device__ __forceinline__ void act(State& st, Smem& sm, int it, int k, float p) {
  if constexpr (ACT == 0)      st.s1a[it] = fminf(p, 1.0e6f);
  else if constexpr (ACT == 1) st.s1b[it] = fminf(p, 1.0e6f);
  else if constexpr (ACT == 2) { st.s1a[it] = fminf(st.s1a[it], p); st.s1b[it] = fminf(st.s1b[it], p); }
  else if constexpr (ACT == 3) st.s2a[it] = fminf(st.s1a[it], p);
  else if constexpr (ACT == 4) st.s2b[it] = fminf(st.s1a[it], p);
  else if constexpr (ACT == 5) st.s2a[it] = fminf(st.s1b[it], p);
  else if constexpr (ACT == 6) st.s2b[it] = fminf(st.s1b[it], p);
  else if constexpr (ACT == 7) sm.ob[COL * NBANDS + k] = 10.0f * log10f(fmaxf(fminf(st.s2a[it], p), 1.0e-10f));
  else                         sm.ob[COL * NBANDS + k] = 10.0f * log10f(fmaxf(fminf(st.s2b[it], p), 1.0e-10f));
}

// One pass = two windowed frames (A at level LA offset offA, B at LB/offB),
// FFT'd together, unpacked, min-chain actions applied.
template <int LA, int ACTA, int COLA, int LB, int ACTB, int COLB, bool HASB>
__device__ __forceinline__ void pass(Smem& sm, State& st, int offA, int offB) {
  const int tid = threadIdx.x;
  __syncthreads();                          // prior pass done reading z arrays
  // ---- pack: z[n] = w(2n)*frame(2n) + i*w(2n+1)*frame(2n+1) ----
  #pragma unroll
  for (int it = 0; it < 4; ++it) {
    const int n = tid + it * THREADS;
    const int k = 2 * n;
    const float cbe = (it == 0) ? st.W[0].x : (it == 1) ? st.W[0].y : (it == 2) ? -st.W[0].x : -st.W[0].y;
    const float cbo = (it == 0) ? st.co : (it == 1) ? -st.so : (it == 2) ? -st.co : st.so;
    const int p = SW(n);
    {
      constexpr int M = NF >> LA;
      constexpr float ws = (float)(1 << LA) * (0.5f / 1024.0f);
      const int k0 = max(NF - offA, NF - M);
      float re = 0.0f, im = 0.0f;
      if (k >= k0) {
        const float2 xv = *(const float2*)&sm.xs[k - (NF - offA)];
        re = ws * (1.0f - cheb<LA>(cbe)) * xv.x;
        im = ws * (1.0f - cheb<LA>(cbo)) * xv.y;
      }
      sm.zreA[p] = re; sm.zimA[p] = im;
    }
    if constexpr (HASB) {
      constexpr int M = NF >> LB;
      constexpr float ws = (float)(1 << LB) * (0.5f / 1024.0f);
      const int k0 = max(NF - offB, NF - M);
      float re = 0.0f, im = 0.0f;
      if (k >= k0) {
        const float2 xv = *(const float2*)&sm.xs[k - (NF - offB)];
        re = ws * (1.0f - cheb<LB>(cbe)) * xv.x;
        im = ws * (1.0f - cheb<LB>(cbo)) * xv.y;
      }
      sm.zreB[p] = re; sm.zimB[p] = im;
    }
  }

  __syncthreads(); radix4p<9, HASB>(sm, st.W[0]);
  __syncthreads(); radix4p<7, HASB>(sm, st.W[1]);
  __syncthreads(); radix4p<5, HASB>(sm, st.W[2]);
  __syncthreads(); radix4p<3, HASB>(sm, st.W[3]);
  __syncthreads(); radix4p<1, HASB>(sm, st.W[4]);
  __syncthreads();

  // ---- unpack rfft bins (final radix-2 inlined) + power + min-chain ----
  #pragma unroll
  for (int it = 0; it < 5; ++it) {
    if (it < 4 || tid == 0) {
      const int k = tid + it * THREADS;
      const int k1 = k & (NC - 1);
      const int k2 = (NC - k) & (NC - 1);
      const int p1 = SW(posrev10(k1 & 1023));
      const int p2 = SW(posrev10(k2 & 1023));
      const float sA = (k1 & 1024) ? -1.0f : 1.0f;
      const float sB = (k2 & 1024) ? -1.0f : 1.0f;
      float2 U;
      if (it == 0)      U = st.Ub;
      else if (it == 1) U = cmul(st.Ub, make_float2(R2C, -R2C));
      else if (it == 2) U = make_float2(st.Ub.y, -st.Ub.x);
      else if (it == 3) U = cmul(st.Ub, make_float2(-R2C, -R2C));
      else              U = make_float2(-st.Ub.x, -st.Ub.y);
      const float pA = rpow(sm.zreA, sm.zimA, p1, sA, p2, sB, U);
      act<ACTA, COLA>(st, sm, it, k, pA);
      if constexpr (HASB) {
        const float pB = rpow(sm.zreB, sm.zimB, p1, sA, p2, sB, U);
        act<ACTB, COLB>(st, sm, it, k, pB);
      }
    }
  }
}

template <int T0>
__device__ __forceinline__ void store_cols(Smem& sm, float* __restrict__ outb) {
  const int tid = threadIdx.x;
  #pragma unroll
  for (int it = 0; it < 5; ++it) {
    if (it < 4 || tid == 0) {
      const int band = tid + it * THREADS;
      float4 v = make_float4(sm.ob[band], sm.ob[NBANDS + band],
                             sm.ob[2 * NBANDS + band], sm.ob[3 * NBANDS + band]);
      *(float4*)&outb[(size_t)band * 8 + T0] = v;
    }
  }
}

__global__ __launch_bounds__(THREADS, 2) void spec_kernel(const float* __restrict__ x,
                                                          float* __restrict__ out) {
  __shared__ Smem sm;
  State st;
  const int tid = threadIdx.x;
  const int b = blockIdx.x;
  const float* xb = x + (size_t)b * BUF;
  #pragma unroll
  for (int i = tid; i < BUF; i += THREADS) sm.xs[i] = xb[i];
  {
    float sn, cs;
    sincospif((float)tid * (1.0f / 1024.0f), &sn, &cs);         st.W[0] = make_float2(cs, -sn);
    sincospif((float)(tid & 127) * (1.0f / 256.0f), &sn, &cs);  st.W[1] = make_float2(cs, -sn);
    sincospif((float)(tid & 31) * (1.0f / 64.0f), &sn, &cs);    st.W[2] = make_float2(cs, -sn);
    sincospif((float)(tid & 7) * (1.0f / 16.0f), &sn, &cs);     st.W[3] = make_float2(cs, -sn);
    st.W[4] = (tid & 1) ? make_float2(R2C, -R2C) : make_float2(1.0f, 0.0f);
    sincospif((float)tid * (1.0f / 2048.0f), &sn, &cs);         st.Ub = make_float2(cs, -sn);
    sincospif((float)(2 * tid + 1) * (1.0f / 2048.0f), &sn, &cs); st.co = cs; st.so = sn;
  }
  float* outb = out + (size_t)b * (NBANDS * 8);

  // NOTE on pack-window bases: cheb<L> needs cos at lvl0 resolution for even
  // samples: cos(pi*k/2048) with k=2n -> cos(pi*n/1024) = W[0].x pattern over
  // quadrants (it selects +-cos/+-sin); odd samples use co/so likewise.

  // Frames: lvl0 off=1024; lvl1 off=512*(i+1); lvl2 off=256*(i+1); lvl3 off=128*(i+1)
  pass<1, 0, 0,  1, 1, 0, true >(sm, st, 512, 1024);   // s1a=l1_0, s1b=l1_1
  pass<0, 2, 0,  2, 3, 0, true >(sm, st, 1024, 256);   // fold lvl0; s2a=min(s1a,l2_0)
  pass<2, 4, 0,  3, 7, 0, true >(sm, st, 512, 128);    // s2b=min(s1a,l2_1); ob0=dB(s2a,l3_0)
  pass<3, 7, 1,  3, 8, 2, true >(sm, st, 256, 384);    // ob1=dB(s2a,l3_1); ob2=dB(s2b,l3_2)
  pass<3, 8, 3,  2, 5, 0, true >(sm, st, 512, 768);    // ob3=dB(s2b,l3_3); s2a=min(s1b,l2_2)
  store_cols<0>(sm, outb);
  pass<2, 6, 0,  3, 7, 0, true >(sm, st, 1024, 640);   // s2b=min(s1b,l2_3); ob0=dB(s2a,l3_4)
  pass<3, 7, 1,  3, 8, 2, true >(sm, st, 768, 896);    // ob1=dB(s2a,l3_5); ob2=dB(s2b,l3_6)
  pass<3, 8, 3,  0, 0, 0, false>(sm, st, 1024, 0);     // ob3=dB(s2b,l3_7)
  store_cols<4>(sm, outb);
}

extern "C" void kernel_launch(void* const* d_in, const int* in_sizes, int n_in,
                              void* d_out, int out_size, void* d_ws, size_t ws_size,
                              hipStream_t stream) {
  const float* x = (const float*)d_in[0];
  float* out = (float*)d_out;
  const int B = in_sizes[0] / BUF;
  hipLaunchKernelGGL(spec_kernel, dim3(B), dim3(THREADS), 0, stream, x, out);
}

// Round 6
// 102.206 us; speedup vs baseline: 1.9287x; 1.2272x over previous
//
#include <hip/hip_runtime.h>
#include <math.h>

#define NBANDS 2049
#define NF 4096      // real frame size
#define NC 2048      // complex FFT size (rfft via packed complex)
#define BUF 1024     // input samples per batch row
#define THREADS 512
#define R2C 0.70710678118654752f

// LDS bank swizzle: bijective on [0,2048); SW(e^1) == SW(e)^1
__device__ __forceinline__ int SW(int i) { return i ^ (i >> 2) ^ (i >> 6); }

// digit-reversed position after 5 radix-4 stages (final radix-2 folded out)
__device__ __forceinline__ int posrev10(int j) {
  return ((j & 3) << 9) | (((j >> 2) & 3) << 7) | (((j >> 4) & 3) << 5) |
         (((j >> 6) & 3) << 3) | (((j >> 8) & 3) << 1);
}

struct Smem {
  float xs[BUF];                 // 4 KB
  float zreA[NC], zimA[NC];      // 16 KB
  float zreB[NC], zimB[NC];      // 16 KB
  float ob[4 * NBANDS];          // 32 KB output-column staging
};                               // ~68 KB -> 2 blocks/CU

struct State {
  float2 W[5];                   // per-thread stage twiddles
  float2 Ub;                     // exp(-pi*i*tid/2048)
  float2 U1;                     // Ub * exp(-i*pi/4)
  float so;                      // sin(pi*(2*tid+1)/2048) (odd window base)
  float s1a[5], s1b[5];          // running mins after lvl1 (two subtrees)
  float s2a[5], s2b[5];          // running mins after lvl2 (two live nodes)
};

__device__ __forceinline__ float2 cmul(float2 a, float2 b) {
  return make_float2(a.x * b.x - a.y * b.y, a.x * b.y + a.y * b.x);
}

// Chebyshev cos-doubling: cos(t) -> cos(2^L * t)
template <int L>
__device__ __forceinline__ float cheb(float c) {
  #pragma unroll
  for (int i = 0; i < L; ++i) c = 2.0f * c * c - 1.0f;
  return c;
}

// Fused pack + pruned first radix-4 stage (span 512).
// Complex support of every frame is <= 512, so only tap3 (n+1536) is nonzero:
// y = {d, i*d*W, -d*W^2, -i*d*W^3}, d = windowed sample pair read from xs.
template <int L>
__device__ __forceinline__ void fused_s1(float* __restrict__ re, float* __restrict__ im,
                                         const Smem& sm, const State& st, int off) {
  const int n = threadIdx.x;
  constexpr int M = NF >> L;
  constexpr float ws = (float)(1 << L) * (0.5f / 1024.0f);
  const int lo = 512 - (min(off, M) >> 1);
  float dr = 0.0f, di = 0.0f;
  if (n >= lo) {
    const int idx = 2 * n + off - 1024;          // even, in [0, off)
    const float2 xv = *(const float2*)&sm.xs[idx];
    // cos(pi*k/2048) at k=2(n+1536) equals sin(pi*n/1024) = -W0.y;
    // odd sample uses sin(pi*(2n+1)/2048) = so.
    const float cE = cheb<L>(-st.W[0].y);
    const float cO = cheb<L>(st.so);
    dr = ws * (1.0f - cE) * xv.x;
    di = ws * (1.0f - cO) * xv.y;
  }
  const float2 W = st.W[0];
  const float2 W2 = make_float2(W.x * W.x - W.y * W.y, 2.0f * W.x * W.y);
  const float2 W3 = cmul(W, W2);
  const int p0 = SW(n), p1 = SW(n + 512), p2 = SW(n + 1024), p3 = SW(n + 1536);
  re[p0] = dr;                       im[p0] = di;
  re[p1] = -di * W.x - dr * W.y;     im[p1] = -di * W.y + dr * W.x;   // (i d) W
  re[p2] = -(dr * W2.x - di * W2.y); im[p2] = -(dr * W2.y + di * W2.x); // -d W^2
  re[p3] =  di * W3.x + dr * W3.y;   im[p3] =  di * W3.y - dr * W3.x; // (-i d) W^3
}

__device__ __forceinline__ void bfly4(float* __restrict__ re, float* __restrict__ im,
                                      int i0, int i1, int i2, int i3,
                                      float2 W, float2 W2, float2 W3) {
  float ar = re[i0], ai = im[i0];
  float br = re[i1], bi = im[i1];
  float cr = re[i2], ci = im[i2];
  float dr = re[i3], di = im[i3];
  float t0r = ar + cr, t0i = ai + ci;
  float t1r = ar - cr, t1i = ai - ci;
  float t2r = br + dr, t2i = bi + di;
  float t3r = br - dr, t3i = bi - di;
  re[i0] = t0r + t2r; im[i0] = t0i + t2i;
  float y1r = t1r + t3i, y1i = t1i - t3r;                  // (t1 - i*t3)
  re[i1] = y1r * W.x - y1i * W.y;  im[i1] = y1r * W.y + y1i * W.x;
  float y2r = t0r - t2r, y2i = t0i - t2i;
  re[i2] = y2r * W2.x - y2i * W2.y; im[i2] = y2r * W2.y + y2i * W2.x;
  float y3r = t1r - t3i, y3i = t1i + t3r;                  // (t1 + i*t3)
  re[i3] = y3r * W3.x - y3i * W3.y; im[i3] = y3r * W3.y + y3i * W3.x;
}

template <int LM, bool HASB>
__device__ __forceinline__ void radix4p(Smem& sm, float2 W) {
  const int j = threadIdx.x;
  const int m = 1 << LM;
  const int base = ((j >> LM) << (LM + 2)) | (j & (m - 1));
  const int i0 = SW(base), i1 = SW(base + m), i2 = SW(base + 2 * m), i3 = SW(base + 3 * m);
  float2 W2 = make_float2(W.x * W.x - W.y * W.y, 2.0f * W.x * W.y);
  float2 W3 = cmul(W, W2);
  bfly4(sm.zreA, sm.zimA, i0, i1, i2, i3, W, W2, W3);
  if constexpr (HASB) bfly4(sm.zreB, sm.zimB, i0, i1, i2, i3, W, W2, W3);
}

// Shared-read pair unpack: bins kp and 2048-kp read the same Z values.
// p(kp) = |E + U*O|^2, p(2048-kp) = |E - U*O|^2.
__device__ __forceinline__ void pair_powers(const float* __restrict__ re,
                                            const float* __restrict__ im,
                                            int kp, float2 U, float& pp, float& pm) {
  const int k1 = kp & (NC - 1);
  const int k2 = (NC - kp) & (NC - 1);
  const int q1 = SW(posrev10(k1 & 1023));
  const int q2 = SW(posrev10(k2 & 1023));
  const float s1 = (k1 & 1024) ? -1.0f : 1.0f;
  const float s2 = (k2 & 1024) ? -1.0f : 1.0f;
  const float zkr = re[q1] + s1 * re[q1 ^ 1];
  const float zki = im[q1] + s1 * im[q1 ^ 1];
  const float zmr = re[q2] + s2 * re[q2 ^ 1];
  const float zmi = im[q2] + s2 * im[q2 ^ 1];
  const float Ex = 0.5f * (zkr + zmr), Ey = 0.5f * (zki - zmi);
  const float Ox = 0.5f * (zki + zmi), Oy = -0.5f * (zkr - zmr);
  const float Vx = U.x * Ox - U.y * Oy, Vy = U.x * Oy + U.y * Ox;
  const float ax = Ex + Vx, ay = Ey + Vy;
  const float bx = Ex - Vx, by = Ey - Vy;
  pp = ax * ax + ay * ay;
  pm = bx * bx + by * by;
}

// ACT: 0 s1a=min(p,1e6); 1 s1b=min(p,1e6); 2 lvl0 fold into s1a&s1b;
//      3 s2a=min(s1a,p); 4 s2b=min(s1a,p); 5 s2a=min(s1b,p); 6 s2b=min(s1b,p);
//      7 ob[COL]=dB(min(s2a,p)); 8 ob[COL]=dB(min(s2b,p))
template <int ACT, int COL, int SLOT>
__device__ __forceinline__ void act(State& st, Smem& sm, int bin, float p) {
  if constexpr (ACT == 0)      st.s1a[SLOT] = fminf(p, 1.0e6f);
  else if constexpr (ACT == 1) st.s1b[SLOT] = fminf(p, 1.0e6f);
  else if constexpr (ACT == 2) { st.s1a[SLOT] = fminf(st.s1a[SLOT], p); st.s1b[SLOT] = fminf(st.s1b[SLOT], p); }
  else if constexpr (ACT == 3) st.s2a[SLOT] = fminf(st.s1a[SLOT], p);
  else if constexpr (ACT == 4) st.s2b[SLOT] = fminf(st.s1a[SLOT], p);
  else if constexpr (ACT == 5) st.s2a[SLOT] = fminf(st.s1b[SLOT], p);
  else if constexpr (ACT == 6) st.s2b[SLOT] = fminf(st.s1b[SLOT], p);
  else if constexpr (ACT == 7) sm.ob[COL * NBANDS + bin] = 10.0f * log10f(fmaxf(fminf(st.s2a[SLOT], p), 1.0e-10f));
  else                         sm.ob[COL * NBANDS + bin] = 10.0f * log10f(fmaxf(fminf(st.s2b[SLOT], p), 1.0e-10f));
}

template <int ACT, int COL>
__device__ __forceinline__ void unpack_frame(const float* __restrict__ re,
                                             const float* __restrict__ im,
                                             State& st, Smem& sm) {
  const int t = threadIdx.x;
  float pp, pm;
  pair_powers(re, im, t, st.Ub, pp, pm);
  act<ACT, COL, 0>(st, sm, t, pp);
  act<ACT, COL, 1>(st, sm, 2048 - t, pm);
  pair_powers(re, im, 512 + t, st.U1, pp, pm);
  act<ACT, COL, 2>(st, sm, 512 + t, pp);
  act<ACT, COL, 3>(st, sm, 1536 - t, pm);
  if (t == 0) {
    // bin 1024: Z[1024] = D[0] - D[1]; p = |Z|^2
    const float zr = re[0] - re[1];
    const float zi = im[0] - im[1];
    act<ACT, COL, 4>(st, sm, 1024, zr * zr + zi * zi);
  }
}

// One pass = two windowed frames, FFT'd together, unpacked, min-chain applied.
template <int LA, int ACTA, int COLA, int LB, int ACTB, int COLB, bool HASB>
__device__ __forceinline__ void pass(Smem& sm, State& st, int offA, int offB) {
  __syncthreads();                          // prior pass done reading z arrays
  fused_s1<LA>(sm.zreA, sm.zimA, sm, st, offA);
  if constexpr (HASB) fused_s1<LB>(sm.zreB, sm.zimB, sm, st, offB);
  __syncthreads(); radix4p<7, HASB>(sm, st.W[1]);
  __syncthreads(); radix4p<5, HASB>(sm, st.W[2]);
  __syncthreads(); radix4p<3, HASB>(sm, st.W[3]);
  __syncthreads(); radix4p<1, HASB>(sm, st.W[4]);
  __syncthreads();
  unpack_frame<ACTA, COLA>(sm.zreA, sm.zimA, st, sm);
  if constexpr (HASB) unpack_frame<ACTB, COLB>(sm.zreB, sm.zimB, st, sm);
}

template <int T0>
__device__ __forceinline__ void store_cols(Smem& sm, float* __restrict__ outb) {
  __syncthreads();                          // ob written by other threads
  const int tid = threadIdx.x;
  #pragma unroll
  for (int it = 0; it < 5; ++it) {
    if (it < 4 || tid == 0) {
      const int band = tid + it * THREADS;
      float4 v = make_float4(sm.ob[band], sm.ob[NBANDS + band],
                             sm.ob[2 * NBANDS + band], sm.ob[3 * NBANDS + band]);
      *(float4*)&outb[(size_t)band * 8 + T0] = v;
    }
  }
}

__global__ __launch_bounds__(THREADS, 2) void spec_kernel(const float* __restrict__ x,
                                                          float* __restrict__ out) {
  __shared__ Smem sm;
  State st;
  const int tid = threadIdx.x;
  const int b = blockIdx.x;
  const float* xb = x + (size_t)b * BUF;
  #pragma unroll
  for (int i = tid; i < BUF; i += THREADS) sm.xs[i] = xb[i];
  {
    float sn, cs;
    sincospif((float)tid * (1.0f / 1024.0f), &sn, &cs);         st.W[0] = make_float2(cs, -sn);
    sincospif((float)(tid & 127) * (1.0f / 256.0f), &sn, &cs);  st.W[1] = make_float2(cs, -sn);
    sincospif((float)(tid & 31) * (1.0f / 64.0f), &sn, &cs);    st.W[2] = make_float2(cs, -sn);
    sincospif((float)(tid & 7) * (1.0f / 16.0f), &sn, &cs);     st.W[3] = make_float2(cs, -sn);
    st.W[4] = (tid & 1) ? make_float2(R2C, -R2C) : make_float2(1.0f, 0.0f);
    sincospif((float)tid * (1.0f / 2048.0f), &sn, &cs);         st.Ub = make_float2(cs, -sn);
    st.U1 = cmul(st.Ub, make_float2(R2C, -R2C));
    sincospif((float)(2 * tid + 1) * (1.0f / 2048.0f), &sn, &cs); st.so = sn;
  }
  float* outb = out + (size_t)b * (NBANDS * 8);

  // Frames: lvl0 off=1024; lvl1 off=512*(i+1); lvl2 off=256*(i+1); lvl3 off=128*(i+1)
  pass<1, 0, 0,  1, 1, 0, true >(sm, st, 512, 1024);   // s1a=l1_0, s1b=l1_1
  pass<0, 2, 0,  2, 3, 0, true >(sm, st, 1024, 256);   // fold lvl0; s2a=min(s1a,l2_0)
  pass<2, 4, 0,  3, 7, 0, true >(sm, st, 512, 128);    // s2b=min(s1a,l2_1); ob0=dB(s2a,l3_0)
  pass<3, 7, 1,  3, 8, 2, true >(sm, st, 256, 384);    // ob1=dB(s2a,l3_1); ob2=dB(s2b,l3_2)
  pass<3, 8, 3,  2, 5, 0, true >(sm, st, 512, 768);    // ob3=dB(s2b,l3_3); s2a=min(s1b,l2_2)
  store_cols<0>(sm, outb);
  pass<2, 6, 0,  3, 7, 0, true >(sm, st, 1024, 640);   // s2b=min(s1b,l2_3); ob0=dB(s2a,l3_4)
  pass<3, 7, 1,  3, 8, 2, true >(sm, st, 768, 896);    // ob1=dB(s2a,l3_5); ob2=dB(s2b,l3_6)
  pass<3, 8, 3,  0, 0, 0, false>(sm, st, 1024, 0);     // ob3=dB(s2b,l3_7)
  store_cols<4>(sm, outb);
}

extern "C" void kernel_launch(void* const* d_in, const int* in_sizes, int n_in,
                              void* d_out, int out_size, void* d_ws, size_t ws_size,
                              hipStream_t stream) {
  const float* x = (const float*)d_in[0];
  float* out = (float*)d_out;
  const int B = in_sizes[0] / BUF;
  hipLaunchKernelGGL(spec_kernel, dim3(B), dim3(THREADS), 0, stream, x, out);
}